// Round 1
// baseline (3752.168 us; speedup 1.0000x reference)
//
#include <hip/hip_runtime.h>

#define NB 8
#define NC 256
#define LU 16384
#define LD 32768

typedef long long i64;

// ---------------------------------------------------------------------------
// Composite conv weights: Wc[t][o][c] = sum_m psi2_w[o,m,t] * psi1_w[m,c]
// ---------------------------------------------------------------------------
__global__ __launch_bounds__(256) void make_wc_kernel(const float* __restrict__ psi2w,
                                                      const float* __restrict__ psi1w,
                                                      float* __restrict__ Wc) {
    int o = blockIdx.x & 255, tp = blockIdx.x >> 8;
    int c = threadIdx.x;
    float s = 0.f;
    for (int m = 0; m < NC; ++m)
        s += psi2w[(o * NC + m) * 3 + tp] * psi1w[m * NC + c];
    Wc[(tp * NC + o) * NC + c] = s;
}

// cb[o] = psi2_b[o] + sum_t sum_m psi2_w[o,m,t]*psi1_b[m]; tapb0 = tap-0 part
__global__ __launch_bounds__(256) void make_cb_kernel(const float* __restrict__ psi2w,
                                                      const float* __restrict__ psi1b,
                                                      const float* __restrict__ psi2b,
                                                      float* __restrict__ cb,
                                                      float* __restrict__ tapb0) {
    int o = threadIdx.x;
    float full = psi2b[o];
    float t0 = 0.f;
    for (int tp = 0; tp < 3; ++tp) {
        float s = 0.f;
        for (int m = 0; m < NC; ++m) s += psi2w[(o * NC + m) * 3 + tp] * psi1b[m];
        full += s;
        if (tp == 0) t0 = s;
    }
    cb[o] = full;
    tapb0[o] = t0;
}

// ---------------------------------------------------------------------------
// Generic 1x1-conv GEMM:  Y[b,o,n] = sum_c W[b*wbs + o*K + c] * Xget(b,c,n)
//                                    + bscale*bias[o] + R[b,o,n]
// Xget: PAIR ? X[b,c,2n] + X[b,c,2n+1] : X[b,c,n]
// X channel stride = Lx (Ly or 2*Ly); X batch stride = xbs (explicit).
// ---------------------------------------------------------------------------
template <int PAIR>
__global__ __launch_bounds__(256) void gemm1x1(const float* __restrict__ X, i64 xbs,
                                               const float* __restrict__ W, i64 wbs,
                                               const float* __restrict__ bias, float bscale,
                                               const float* __restrict__ R,
                                               float* __restrict__ Y,
                                               int K, int O, int Ly) {
    const int n0 = blockIdx.x * 64;
    const int o0 = blockIdx.y * 64;
    const int b = blockIdx.z;
    const int t = threadIdx.x;
    const int tr = t >> 4, tc = t & 15;
    const i64 Lx = PAIR ? (i64)Ly * 2 : (i64)Ly;

    __shared__ float Ws[16][68];  // [k][m], pad 68 => 16B-aligned float4 rows
    __shared__ float Xs[16][68];  // [k][n]

    float acc[4][4] = {};
    const float* Xb = X + (i64)b * xbs;
    const float* Wb = W + (i64)b * wbs;

    for (int k0 = 0; k0 < K; k0 += 16) {
#pragma unroll
        for (int i = 0; i < 4; ++i) {
            int j = i * 256 + t;
            int kk = j & 15, m = j >> 4;
            Ws[kk][m] = Wb[(i64)(o0 + m) * K + (k0 + kk)];
        }
#pragma unroll
        for (int i = 0; i < 4; ++i) {
            int r = (t >> 6) + i * 4;
            int col = t & 63;
            const float* xp = Xb + (i64)(k0 + r) * Lx;
            float v;
            if (PAIR) {
                i64 g = 2 * (i64)(n0 + col);
                v = xp[g] + xp[g + 1];
            } else {
                v = xp[n0 + col];
            }
            Xs[r][col] = v;
        }
        __syncthreads();
#pragma unroll
        for (int kk = 0; kk < 16; ++kk) {
            float4 a4 = *(const float4*)&Ws[kk][tr * 4];
            float4 x4 = *(const float4*)&Xs[kk][tc * 4];
            float av[4] = {a4.x, a4.y, a4.z, a4.w};
            float xv[4] = {x4.x, x4.y, x4.z, x4.w};
#pragma unroll
            for (int mi = 0; mi < 4; ++mi)
#pragma unroll
                for (int ni = 0; ni < 4; ++ni) acc[mi][ni] += av[mi] * xv[ni];
        }
        __syncthreads();
    }
#pragma unroll
    for (int mi = 0; mi < 4; ++mi) {
        int m = o0 + tr * 4 + mi;
        float bv = bias ? bscale * bias[m] : 0.f;
        i64 idx = ((i64)b * O + m) * Ly + n0 + tc * 4;
        float4 o4;
        o4.x = acc[mi][0] + bv;
        o4.y = acc[mi][1] + bv;
        o4.z = acc[mi][2] + bv;
        o4.w = acc[mi][3] + bv;
        if (R) {
            float4 r4 = *(const float4*)&R[idx];
            o4.x += r4.x; o4.y += r4.y; o4.z += r4.z; o4.w += r4.w;
        }
        *(float4*)&Y[idx] = o4;
    }
}

// ---------------------------------------------------------------------------
// Composed conv3 stride2: Y[b,o,j] += sum_t sum_c Wc[t][o][c]*X[b,c,2j-1+t]
//                                     + cb[o] - (j==0 ? tapb0[o] : 0)
// (Y pre-holds the maxpool result; in-place accumulate.)
// ---------------------------------------------------------------------------
__global__ __launch_bounds__(256) void conv3s2_kernel(const float* __restrict__ X,
                                                      const float* __restrict__ Wc,
                                                      const float* __restrict__ cb,
                                                      const float* __restrict__ tapb0,
                                                      float* __restrict__ Y) {
    const int n0 = blockIdx.x * 64;
    const int o0 = blockIdx.y * 64;
    const int b = blockIdx.z;
    const int t = threadIdx.x;
    const int tr = t >> 4, tc = t & 15;

    __shared__ float Ws[16][68];
    __shared__ float Xs[16][68];

    float acc[4][4] = {};
    const float* Xb = X + (i64)b * NC * LD;

    for (int tap = 0; tap < 3; ++tap) {
        const float* Wt = Wc + (i64)tap * NC * NC;
        for (int k0 = 0; k0 < NC; k0 += 16) {
#pragma unroll
            for (int i = 0; i < 4; ++i) {
                int j = i * 256 + t;
                int kk = j & 15, m = j >> 4;
                Ws[kk][m] = Wt[(i64)(o0 + m) * NC + (k0 + kk)];
            }
#pragma unroll
            for (int i = 0; i < 4; ++i) {
                int r = (t >> 6) + i * 4;
                int col = t & 63;
                i64 g = 2 * (i64)(n0 + col) - 1 + tap;
                Xs[r][col] = (g < 0) ? 0.f : Xb[(i64)(k0 + r) * LD + g];
            }
            __syncthreads();
#pragma unroll
            for (int kk = 0; kk < 16; ++kk) {
                float4 a4 = *(const float4*)&Ws[kk][tr * 4];
                float4 x4 = *(const float4*)&Xs[kk][tc * 4];
                float av[4] = {a4.x, a4.y, a4.z, a4.w};
                float xv[4] = {x4.x, x4.y, x4.z, x4.w};
#pragma unroll
                for (int mi = 0; mi < 4; ++mi)
#pragma unroll
                    for (int ni = 0; ni < 4; ++ni) acc[mi][ni] += av[mi] * xv[ni];
            }
            __syncthreads();
        }
    }
#pragma unroll
    for (int mi = 0; mi < 4; ++mi) {
        int m = o0 + tr * 4 + mi;
        float cbase = cb[m];
        float t0 = tapb0[m];
#pragma unroll
        for (int ni = 0; ni < 4; ++ni) {
            int n = n0 + tc * 4 + ni;
            i64 idx = ((i64)b * NC + m) * LU + n;
            float bv = cbase - (n == 0 ? t0 : 0.f);
            Y[idx] += acc[mi][ni] + bv;
        }
    }
}

// ---------------------------------------------------------------------------
// Split-K scores: Sp[s][b][c][d] = sum_{l in chunk s} Q[b,c,l]*Km[b,d,l]
// ---------------------------------------------------------------------------
__global__ __launch_bounds__(256) void scores_split(const float* __restrict__ Q, i64 qbs,
                                                    const float* __restrict__ Km, i64 kbs,
                                                    float* __restrict__ Sp, int L, int CHUNK) {
    int tile = blockIdx.x;
    int c0 = (tile >> 2) * 64, d0 = (tile & 3) * 64;
    int s = blockIdx.y, b = blockIdx.z;
    int l0 = s * CHUNK;
    int t = threadIdx.x, tr = t >> 4, tc = t & 15;

    __shared__ float Qs[16][68];  // [l][c] transposed-store
    __shared__ float Ks[16][68];  // [l][d]

    float acc[4][4] = {};
    const float* Qb = Q + (i64)b * qbs;
    const float* Kb = Km + (i64)b * kbs;

    for (int lt = 0; lt < CHUNK; lt += 16) {
#pragma unroll
        for (int i = 0; i < 4; ++i) {
            int j = i * 256 + t;
            int kk = j & 15, m = j >> 4;
            Qs[kk][m] = Qb[(i64)(c0 + m) * L + l0 + lt + kk];
            Ks[kk][m] = Kb[(i64)(d0 + m) * L + l0 + lt + kk];
        }
        __syncthreads();
#pragma unroll
        for (int kk = 0; kk < 16; ++kk) {
            float4 a4 = *(const float4*)&Qs[kk][tr * 4];
            float4 x4 = *(const float4*)&Ks[kk][tc * 4];
            float av[4] = {a4.x, a4.y, a4.z, a4.w};
            float xv[4] = {x4.x, x4.y, x4.z, x4.w};
#pragma unroll
            for (int mi = 0; mi < 4; ++mi)
#pragma unroll
                for (int ni = 0; ni < 4; ++ni) acc[mi][ni] += av[mi] * xv[ni];
        }
        __syncthreads();
    }
#pragma unroll
    for (int mi = 0; mi < 4; ++mi) {
        int c = c0 + tr * 4 + mi;
        i64 idx = (((i64)s * NB + b) * NC + c) * NC + d0 + tc * 4;
        float4 o4 = {acc[mi][0], acc[mi][1], acc[mi][2], acc[mi][3]};
        *(float4*)&Sp[idx] = o4;
    }
}

// Reduce split-K partials + softmax over d (scale 1/16). One block per (b,c).
__global__ __launch_bounds__(256) void softmax_rows(const float* __restrict__ Sp,
                                                    float* __restrict__ S, int SPLIT) {
    int bc = blockIdx.x;
    int b = bc >> 8, c = bc & 255;
    int d = threadIdx.x;
    float v = 0.f;
    for (int s = 0; s < SPLIT; ++s)
        v += Sp[(((i64)s * NB + b) * NC + c) * NC + d];
    v *= (1.0f / 16.0f);
    __shared__ float red[256];
    red[d] = v;
    __syncthreads();
    for (int off = 128; off; off >>= 1) {
        if (d < off) red[d] = fmaxf(red[d], red[d + off]);
        __syncthreads();
    }
    float mx = red[0];
    __syncthreads();
    float e = expf(v - mx);
    red[d] = e;
    __syncthreads();
    for (int off = 128; off; off >>= 1) {
        if (d < off) red[d] += red[d + off];
        __syncthreads();
    }
    float sum = red[0];
    S[((i64)b * NC + c) * NC + d] = e / sum;
}

// maxpool3 stride2 (pad 1):  Y[row,j] = max(x[2j-1], x[2j], x[2j+1])
__global__ __launch_bounds__(256) void maxpool_kernel(const float* __restrict__ X,
                                                      float* __restrict__ Y) {
    i64 i = (i64)blockIdx.x * 256 + threadIdx.x;
    if (i >= (i64)NB * NC * LU) return;
    int j = (int)(i & (LU - 1));
    i64 row = i >> 14;
    const float* x = X + row * LD;
    int g = 2 * j;
    float v = x[g];
    if (j > 0) v = fmaxf(v, x[g - 1]);
    v = fmaxf(v, x[g + 1]);
    Y[i] = v;
}

// down_out[b,c,l] = x_d[b,c,l] + ov[b,c,l>>1]   (float4 over l)
__global__ __launch_bounds__(256) void expand_add(const float* __restrict__ Xd,
                                                  const float* __restrict__ OV,
                                                  float* __restrict__ Yd) {
    i64 i4 = (i64)blockIdx.x * 256 + threadIdx.x;
    if (i4 >= (i64)NB * NC * LD / 4) return;
    i64 i = i4 * 4;
    int l = (int)(i & (LD - 1));
    i64 row = i >> 15;
    float4 xv = *(const float4*)(Xd + i);
    float2 ov = *(const float2*)(OV + row * LU + (l >> 1));
    float4 y;
    y.x = xv.x + ov.x;
    y.y = xv.y + ov.x;
    y.z = xv.z + ov.y;
    y.w = xv.w + ov.y;
    *(float4*)(Yd + i) = y;
}

// ---------------------------------------------------------------------------
extern "C" void kernel_launch(void* const* d_in, const int* in_sizes, int n_in,
                              void* d_out, int out_size, void* d_ws, size_t ws_size,
                              hipStream_t stream) {
    const float* x_u = (const float*)d_in[0];
    const float* x_d = (const float*)d_in[1];
    const float* vk_w = (const float*)d_in[2];
    const float* vk_b = (const float*)d_in[3];
    const float* q_w = (const float*)d_in[4];
    const float* q_b = (const float*)d_in[5];
    const float* psi1_w = (const float*)d_in[6];
    const float* psi1_b = (const float*)d_in[7];
    const float* psi2_w = (const float*)d_in[8];
    const float* psi2_b = (const float*)d_in[9];
    const float* phi_w = (const float*)d_in[10];
    const float* phi_b = (const float*)d_in[11];

    float* out_up = (float*)d_out;                      // 8*256*16384
    float* out_dn = out_up + (i64)NB * NC * LU;         // 8*256*32768

    float* A = (float*)d_ws;                            // 33,554,432 f
    float* Cbuf = A + (i64)NB * NC * LU;                // 67,108,864 f
    float* S = Cbuf + (i64)NB * 2 * NC * LU;            // 524,288 f
    float* Wc = S + (i64)NB * NC * NC;                  // 196,608 f
    float* cb = Wc + 3 * NC * NC;                       // 256 f
    float* tapb0 = cb + NC;                             // 256 f

    const int SPLIT = 16;
    const int CHUNK = LU / SPLIT;  // 1024
    float* Sp1 = out_dn;  // 8.39M f scratch, dead before expand_add writes
    float* Sp2 = A;       // A dead after vk_d2u GEMM

    dim3 blk(256);
    const i64 xu_bs = (i64)NC * LU;
    const i64 xd_bs = (i64)NC * LD;
    const i64 vk_bs = (i64)2 * NC * LU;

    // weight prep
    make_wc_kernel<<<768, blk, 0, stream>>>(psi2_w, psi1_w, Wc);
    make_cb_kernel<<<1, blk, 0, stream>>>(psi2_w, psi1_b, psi2_b, cb, tapb0);

    // ---- u2d path -> down_output ----
    // t_u = (I+phi)@x_u + phi_b   -> A
    gemm1x1<0><<<dim3(256, 4, 8), blk, 0, stream>>>(x_u, xu_bs, phi_w, 0, phi_b, 1.f, x_u, A,
                                                    NC, NC, LU);
    // vk_half = vk_w@t_u + vk_b   -> Cbuf  (v: ch 0..255, k: ch 256..511)
    gemm1x1<0><<<dim3(256, 8, 8), blk, 0, stream>>>(A, xu_bs, vk_w, 0, vk_b, 1.f, nullptr, Cbuf,
                                                    NC, 2 * NC, LU);
    // qds = q_w@(x_d[2j]+x_d[2j+1]) + 2*q_b -> A (t_u dead)
    gemm1x1<1><<<dim3(256, 4, 8), blk, 0, stream>>>(x_d, xd_bs, q_w, 0, q_b, 2.f, nullptr, A,
                                                    NC, NC, LU);
    // scores_u2d = qds . k_half ; softmax
    scores_split<<<dim3(16, SPLIT, 8), blk, 0, stream>>>(A, xu_bs, Cbuf + (i64)NC * LU, vk_bs,
                                                         Sp1, LU, CHUNK);
    softmax_rows<<<NB * NC, blk, 0, stream>>>(Sp1, S, SPLIT);
    // ov = attn_u2d @ v_half -> out_up (temp)
    gemm1x1<0><<<dim3(256, 4, 8), blk, 0, stream>>>(Cbuf, vk_bs, S, (i64)NC * NC, nullptr, 0.f,
                                                    nullptr, out_up, NC, NC, LU);
    // down_out = x_d + ov[l>>1]
    expand_add<<<(NB * NC * LD / 4 + 255) / 256, blk, 0, stream>>>(x_d, out_up, out_dn);

    // ---- d2u path -> up_output ----
    // down2up = maxpool(x_d) + composed conv3  -> A
    maxpool_kernel<<<(NB * NC * LU + 255) / 256, blk, 0, stream>>>(x_d, A);
    conv3s2_kernel<<<dim3(256, 4, 8), blk, 0, stream>>>(x_d, Wc, cb, tapb0, A);
    // vk_d2u = vk_w@down2up + vk_b -> Cbuf
    gemm1x1<0><<<dim3(256, 8, 8), blk, 0, stream>>>(A, xu_bs, vk_w, 0, vk_b, 1.f, nullptr, Cbuf,
                                                    NC, 2 * NC, LU);
    // q_u = q_w@x_u + q_b -> out_up (temp; ov dead)
    gemm1x1<0><<<dim3(256, 4, 8), blk, 0, stream>>>(x_u, xu_bs, q_w, 0, q_b, 1.f, nullptr,
                                                    out_up, NC, NC, LU);
    // scores_d2u = q_u . k_d2u ; softmax   (Sp2 = A, dead now)
    scores_split<<<dim3(16, SPLIT, 8), blk, 0, stream>>>(out_up, xu_bs, Cbuf + (i64)NC * LU,
                                                         vk_bs, Sp2, LU, CHUNK);
    softmax_rows<<<NB * NC, blk, 0, stream>>>(Sp2, S, SPLIT);
    // up_out = x_u + attn_d2u @ v_d2u -> out_up (overwrites q_u)
    gemm1x1<0><<<dim3(256, 4, 8), blk, 0, stream>>>(Cbuf, vk_bs, S, (i64)NC * NC, nullptr, 0.f,
                                                    x_u, out_up, NC, NC, LU);
}

// Round 4
// 1233.877 us; speedup vs baseline: 3.0410x; 3.0410x over previous
//
#include <hip/hip_runtime.h>
#include <hip/hip_bf16.h>

#define NB 8
#define NC 256
#define LU 16384
#define LD 32768

typedef long long i64;
typedef unsigned short u16;
typedef __attribute__((ext_vector_type(8))) short bf16x8;
typedef __attribute__((ext_vector_type(4))) float f32x4;

__device__ __forceinline__ u16 f2b(float f) {
    __hip_bfloat16 h = __float2bfloat16(f);
    union { __hip_bfloat16 h; u16 u; } c;
    c.h = h;
    return c.u;
}
__device__ __forceinline__ float b2f(u16 u) {
    union { u16 u; __hip_bfloat16 h; } c;
    c.u = u;
    return __bfloat162float(c.h);
}

// ---------------------------------------------------------------------------
// Weight prep
// ---------------------------------------------------------------------------
__global__ __launch_bounds__(256) void make_wc_kernel(const float* __restrict__ psi2w,
                                                      const float* __restrict__ psi1w,
                                                      float* __restrict__ Wc) {
    int o = blockIdx.x & 255, tp = blockIdx.x >> 8;
    int c = threadIdx.x;
    float s = 0.f;
    for (int m = 0; m < NC; ++m)
        s += psi2w[(o * NC + m) * 3 + tp] * psi1w[m * NC + c];
    Wc[(tp * NC + o) * NC + c] = s;
}

__global__ __launch_bounds__(256) void make_cb_kernel(const float* __restrict__ psi2w,
                                                      const float* __restrict__ psi1b,
                                                      const float* __restrict__ psi2b,
                                                      float* __restrict__ cb,
                                                      float* __restrict__ tapb0) {
    int o = threadIdx.x;
    float full = psi2b[o];
    float t0 = 0.f;
    for (int tp = 0; tp < 3; ++tp) {
        float s = 0.f;
        for (int m = 0; m < NC; ++m) s += psi2w[(o * NC + m) * 3 + tp] * psi1b[m];
        full += s;
        if (tp == 0) t0 = s;
    }
    cb[o] = full;
    tapb0[o] = t0;
}

// Wstack[o][0..255]=Wc[1] (tap x[2j]), [256..511]=Wc[0] (x[2j-1]), [512..767]=Wc[2] (x[2j+1])
__global__ __launch_bounds__(256) void make_wstack(const float* __restrict__ Wc,
                                                   u16* __restrict__ Ws) {
    int o = blockIdx.x, c = threadIdx.x;
    Ws[(i64)o * 768 + 0 + c]   = f2b(Wc[(1 * NC + o) * NC + c]);
    Ws[(i64)o * 768 + 256 + c] = f2b(Wc[(0 * NC + o) * NC + c]);
    Ws[(i64)o * 768 + 512 + c] = f2b(Wc[(2 * NC + o) * NC + c]);
}

// W_vku = vk_w @ (I + phi)  (bf16, u2d path ONLY), bvku = vk_b + vk_w @ phi_b
__global__ __launch_bounds__(256) void make_wvku(const float* __restrict__ vkw,
                                                 const float* __restrict__ phiw,
                                                 const float* __restrict__ vkb,
                                                 const float* __restrict__ phib,
                                                 u16* __restrict__ Wvku,
                                                 float* __restrict__ bvku) {
    int o = blockIdx.x, c = threadIdx.x;
    float s = vkw[o * NC + c];
    float bs = 0.f;
    for (int m = 0; m < NC; ++m) {
        float w = vkw[o * NC + m];
        s += w * phiw[m * NC + c];
        bs += w * phib[m];
    }
    Wvku[(i64)o * NC + c] = f2b(s);
    if (c == 0) bvku[o] = vkb[o] + bs;
}

// plain fp32 -> bf16 cast (grid = n/256)
__global__ __launch_bounds__(256) void cast_bf16(const float* __restrict__ src,
                                                 u16* __restrict__ dst) {
    i64 i = (i64)blockIdx.x * 256 + threadIdx.x;
    dst[i] = f2b(src[i]);
}

// ---------------------------------------------------------------------------
// Transpose-cast: X fp32 [b][256][L] -> Xt bf16 [b][L][256]; optional pair-sum
// Xds bf16 [b][L/2][256].
// ---------------------------------------------------------------------------
__global__ __launch_bounds__(256) void tcast_kernel(const float* __restrict__ X,
                                                    u16* __restrict__ Xt,
                                                    u16* __restrict__ Xds, int L) {
    const int l0 = blockIdx.x * 64;
    const int c0 = blockIdx.y * 64;
    const int b = blockIdx.z;
    const float* Xb = X + (i64)b * NC * L;
    __shared__ float T[64][65];
    const int t = threadIdx.x;
    const int tc = t >> 4;
    const int tl = (t & 15) * 4;
#pragma unroll
    for (int p = 0; p < 4; ++p) {
        int c = c0 + p * 16 + tc;
        float4 v = *(const float4*)&Xb[(i64)c * L + l0 + tl];
        T[tl + 0][p * 16 + tc] = v.x;
        T[tl + 1][p * 16 + tc] = v.y;
        T[tl + 2][p * 16 + tc] = v.z;
        T[tl + 3][p * 16 + tc] = v.w;
    }
    __syncthreads();
    {
        int lr = t >> 2, cq = (t & 3) * 16;
        union { u16 u[8]; uint4 v; } p0, p1;
#pragma unroll
        for (int i = 0; i < 8; ++i) p0.u[i] = f2b(T[lr][cq + i]);
#pragma unroll
        for (int i = 0; i < 8; ++i) p1.u[i] = f2b(T[lr][cq + 8 + i]);
        u16* Yb = Xt + (i64)b * L * NC + (i64)(l0 + lr) * NC + c0 + cq;
        *(uint4*)Yb = p0.v;
        *(uint4*)(Yb + 8) = p1.v;
    }
    if (Xds != nullptr && t < 128) {
        int jr = t >> 2, cq = (t & 3) * 16;
        union { u16 u[8]; uint4 v; } p0, p1;
#pragma unroll
        for (int i = 0; i < 8; ++i) p0.u[i] = f2b(T[2 * jr][cq + i] + T[2 * jr + 1][cq + i]);
#pragma unroll
        for (int i = 0; i < 8; ++i) p1.u[i] = f2b(T[2 * jr][cq + 8 + i] + T[2 * jr + 1][cq + 8 + i]);
        u16* Yb = Xds + (i64)b * (L / 2) * NC + (i64)(l0 / 2 + jr) * NC + c0 + cq;
        *(uint4*)Yb = p0.v;
        *(uint4*)(Yb + 8) = p1.v;
    }
}

// maxpool3 s2 -> bf16 natural [b][c][j]
__global__ __launch_bounds__(256) void mp_kernel(const float* __restrict__ X,
                                                 u16* __restrict__ MPo) {
    i64 gid = (i64)blockIdx.x * 256 + threadIdx.x;
    int jblk = (int)(gid & 2047);
    i64 row = gid >> 11;
    const float* x = X + row * LD + (i64)jblk * 16;
    float v[16];
    *(float4*)&v[0]  = *(const float4*)&x[0];
    *(float4*)&v[4]  = *(const float4*)&x[4];
    *(float4*)&v[8]  = *(const float4*)&x[8];
    *(float4*)&v[12] = *(const float4*)&x[12];
    float left = (jblk > 0) ? x[-1] : -INFINITY;
    union { u16 u[8]; uint4 q; } o;
#pragma unroll
    for (int j = 0; j < 8; ++j) {
        float a = (j == 0) ? left : v[2 * j - 1];
        o.u[j] = f2b(fmaxf(fmaxf(a, v[2 * j]), v[2 * j + 1]));
    }
    *(uint4*)&MPo[row * LU + (i64)jblk * 8] = o.q;
}

// ---------------------------------------------------------------------------
// bf16 MFMA GEMM: D[m][n] = sum_k A[m][k] * B[n][k]   (128x128 tile, BK=32)
// BSRC: 0 = plain B [n][k]; 1 = conv virtual K=768 over xd_t
// EPI : 0 bf16 natural [m][n]; 1 bf16 transposed [n][m] (+MP, -tapb0@n0);
//       2 fp32 split-K partials; 3 fp32 + RES; 4 fp32 expand-add + RES
// ---------------------------------------------------------------------------
template <int BSRC, int EPI>
__global__ __launch_bounds__(256) void gemm_bf16(
    const u16* __restrict__ A, i64 a_bs, int lda,
    const u16* __restrict__ B, i64 b_bs, int ldb,
    const float* __restrict__ bias, float bscale,
    const u16* __restrict__ MP, const float* __restrict__ TB0,
    const float* __restrict__ RES,
    void* __restrict__ Yv,
    int K, int split) {
    const int n0 = blockIdx.x * 128;
    const int m0 = blockIdx.y * 128;
    int b, k_beg, k_len, pidx;
    if (EPI == 2) {
        int s = blockIdx.z % split;
        b = blockIdx.z / split;
        k_len = K / split;
        k_beg = s * k_len;
        pidx = blockIdx.z;
    } else {
        b = blockIdx.z;
        k_beg = 0;
        k_len = K;
        pidx = 0;
    }

    const int t = threadIdx.x;
    const int lane = t & 63;
    const int wave = t >> 6;
    const int wm = wave >> 1, wn = wave & 1;
    const int srow = t >> 1;         // 0..127: LDS tile row
    const int soff = (t & 1) * 16;   // element offset within 32-wide row

    __shared__ u16 As[128][32];
    __shared__ u16 Bs[128][32];

    f32x4 acc[4][4];
#pragma unroll
    for (int i = 0; i < 4; ++i)
#pragma unroll
        for (int j = 0; j < 4; ++j) acc[i][j] = (f32x4){0.f, 0.f, 0.f, 0.f};

    const u16* Ab = A + (i64)b * a_bs + (i64)(m0 + srow) * lda;
    const u16* Bb = B + (i64)b * b_bs;

    for (int k0 = k_beg; k0 < k_beg + k_len; k0 += 32) {
        uint4 av0 = *(const uint4*)(Ab + k0 + soff);
        uint4 av1 = *(const uint4*)(Ab + k0 + soff + 8);
        uint4 bv0, bv1;
        if (BSRC == 0) {
            const u16* bp = Bb + (i64)(n0 + srow) * ldb + k0 + soff;
            bv0 = *(const uint4*)bp;
            bv1 = *(const uint4*)(bp + 8);
        } else {
            int kk = k0 + soff;        // 16-aligned; whole 16-run in one seg
            int seg = kk >> 8;
            int c = kk & 255;
            int l = 2 * (n0 + srow) + (seg == 0 ? 0 : (seg == 1 ? -1 : 1));
            if (l < 0) {
                bv0 = make_uint4(0u, 0u, 0u, 0u);
                bv1 = bv0;
            } else {
                const u16* bp = Bb + (i64)l * NC + c;
                bv0 = *(const uint4*)bp;
                bv1 = *(const uint4*)(bp + 8);
            }
        }
        __syncthreads();
        *(uint4*)&As[srow][soff] = av0;
        *(uint4*)&As[srow][soff + 8] = av1;
        *(uint4*)&Bs[srow][soff] = bv0;
        *(uint4*)&Bs[srow][soff + 8] = bv1;
        __syncthreads();
        bf16x8 af[4], bfr[4];
#pragma unroll
        for (int i = 0; i < 4; ++i) {
            af[i]  = *(const bf16x8*)&As[wm * 64 + i * 16 + (lane & 15)][(lane >> 4) * 8];
            bfr[i] = *(const bf16x8*)&Bs[wn * 64 + i * 16 + (lane & 15)][(lane >> 4) * 8];
        }
#pragma unroll
        for (int mi = 0; mi < 4; ++mi)
#pragma unroll
            for (int ni = 0; ni < 4; ++ni)
                acc[mi][ni] = __builtin_amdgcn_mfma_f32_16x16x32_bf16(af[mi], bfr[ni],
                                                                      acc[mi][ni], 0, 0, 0);
    }

    const int mb0 = m0 + wm * 64 + ((lane >> 4) << 2);
    const int nb0 = n0 + wn * 64 + (lane & 15);

#pragma unroll
    for (int mi = 0; mi < 4; ++mi) {
#pragma unroll
        for (int ni = 0; ni < 4; ++ni) {
            int n_g = nb0 + ni * 16;
            if (EPI == 0) {
                u16* Y = (u16*)Yv + (i64)b * NC * LU;
#pragma unroll
                for (int r = 0; r < 4; ++r) {
                    int m_g = mb0 + mi * 16 + r;
                    float v = acc[mi][ni][r];
                    if (bias) v += bscale * bias[m_g];
                    Y[(i64)m_g * LU + n_g] = f2b(v);
                }
            } else if (EPI == 1) {
                u16* Y = (u16*)Yv + (i64)b * LU * NC;
                int mbase = mb0 + mi * 16;
                float vv[4];
#pragma unroll
                for (int r = 0; r < 4; ++r) {
                    int m_g = mbase + r;
                    float v = acc[mi][ni][r];
                    if (bias) v += bscale * bias[m_g];
                    if (MP) v += b2f(MP[(i64)b * NC * LU + (i64)m_g * LU + n_g]);
                    if (TB0 && n_g == 0) v -= TB0[m_g];
                    vv[r] = v;
                }
                ushort4 pk;
                pk.x = f2b(vv[0]); pk.y = f2b(vv[1]); pk.z = f2b(vv[2]); pk.w = f2b(vv[3]);
                *(ushort4*)&Y[(i64)n_g * NC + mbase] = pk;
            } else if (EPI == 2) {
                float* Y = (float*)Yv + (i64)pidx * NC * NC;
#pragma unroll
                for (int r = 0; r < 4; ++r) {
                    int m_g = mb0 + mi * 16 + r;
                    Y[(i64)m_g * NC + n_g] = acc[mi][ni][r];
                }
            } else if (EPI == 3) {
                float* Y = (float*)Yv + (i64)b * NC * LU;
                const float* R = RES + (i64)b * NC * LU;
#pragma unroll
                for (int r = 0; r < 4; ++r) {
                    int m_g = mb0 + mi * 16 + r;
                    i64 idx = (i64)m_g * LU + n_g;
                    Y[idx] = acc[mi][ni][r] + R[idx];
                }
            } else {
                float* Y = (float*)Yv + (i64)b * NC * LD;
                const float* R = RES + (i64)b * NC * LD;
#pragma unroll
                for (int r = 0; r < 4; ++r) {
                    int m_g = mb0 + mi * 16 + r;
                    i64 idx = (i64)m_g * LD + 2 * (i64)n_g;
                    float vlo = acc[mi][ni][r] + R[idx];
                    float vhi = acc[mi][ni][r] + R[idx + 1];
                    *(float2*)&Y[idx] = make_float2(vlo, vhi);
                }
            }
        }
    }
}

// Reduce split-K partials, scale 1/16, softmax over d, write bf16 attn[b][c][d].
__global__ __launch_bounds__(256) void softmax_bf16(const float* __restrict__ Sp,
                                                    u16* __restrict__ Attn, int split) {
    int bc = blockIdx.x;
    int b = bc >> 8, c = bc & 255;
    int d = threadIdx.x;
    float v = 0.f;
    for (int s = 0; s < split; ++s)
        v += Sp[((i64)(b * split + s) * NC + c) * NC + d];
    v *= (1.0f / 16.0f);
    __shared__ float red[256];
    red[d] = v;
    __syncthreads();
    for (int off = 128; off; off >>= 1) {
        if (d < off) red[d] = fmaxf(red[d], red[d + off]);
        __syncthreads();
    }
    float mx = red[0];
    __syncthreads();
    float e = expf(v - mx);
    red[d] = e;
    __syncthreads();
    for (int off = 128; off; off >>= 1) {
        if (d < off) red[d] += red[d + off];
        __syncthreads();
    }
    float inv = 1.f / red[0];
    Attn[((i64)b * NC + c) * NC + d] = f2b(e * inv);
}

// ---------------------------------------------------------------------------
extern "C" void kernel_launch(void* const* d_in, const int* in_sizes, int n_in,
                              void* d_out, int out_size, void* d_ws, size_t ws_size,
                              hipStream_t stream) {
    const float* x_u = (const float*)d_in[0];
    const float* x_d = (const float*)d_in[1];
    const float* vk_w = (const float*)d_in[2];
    const float* vk_b = (const float*)d_in[3];
    const float* q_w = (const float*)d_in[4];
    const float* q_b = (const float*)d_in[5];
    const float* psi1_w = (const float*)d_in[6];
    const float* psi1_b = (const float*)d_in[7];
    const float* psi2_w = (const float*)d_in[8];
    const float* psi2_b = (const float*)d_in[9];
    const float* phi_w = (const float*)d_in[10];
    const float* phi_b = (const float*)d_in[11];

    const i64 UNIT = 67108864;  // 64 MiB
    char* ws = (char*)d_ws;

    u16* xd_t    = (u16*)(ws);             // [0,2U)  dead after conv3
    u16* xu_t    = (u16*)(ws);             // R0 (after xd_t dead)
    u16* v_u2d_t = (u16*)(ws + UNIT);      // R1, dead after PV-down
    u16* k_d2u   = (u16*)(ws + UNIT);      // R1 reuse
    u16* xds_t   = (u16*)(ws + 2 * UNIT);  // R2, dead after qds GEMM
    u16* v_d2u_t = (u16*)(ws + 2 * UNIT);  // R2 reuse
    u16* mp      = (u16*)(ws + 3 * UNIT);  // R3, dead after conv3
    u16* k_u2d   = (u16*)(ws + 3 * UNIT);  // R3 reuse
    u16* d2u_t   = (u16*)(ws + 4 * UNIT);  // R4, dead after vk_d2u
    u16* q_u     = (u16*)(ws + 4 * UNIT);  // R4 reuse

    char* sm = ws + 5 * UNIT;
    float* Wc32  = (float*)sm; sm += 786432;
    float* cb    = (float*)sm; sm += 1024;
    float* tapb0 = (float*)sm; sm += 1024;
    u16* Wstack  = (u16*)sm;   sm += 393216;
    u16* Wvku    = (u16*)sm;   sm += 262144;   // composed vk@(I+phi): u2d path ONLY
    float* bvku  = (float*)sm; sm += 2048;
    u16* Qw      = (u16*)sm;   sm += 131072;
    u16* Wvk     = (u16*)sm;   sm += 262144;   // plain vk_w: d2u path
    u16* attn1   = (u16*)sm;   sm += 1048576;
    u16* attn2   = (u16*)sm;   sm += 1048576;

    float* out_up = (float*)d_out;
    float* out_dn = out_up + (i64)NB * NC * LU;
    float* Sp  = (float*)d_out;                    // partials alias out_up
    u16* qds   = (u16*)((char*)d_out + 2 * UNIT);  // alias out_dn head

    const int SPLIT = 16;
    dim3 blk(256);
    dim3 g128(128, 2, 8);
    dim3 gS(2, 2, 8 * SPLIT);
    const i64 act_bs = (i64)LU * NC;
    const i64 cl_bs  = (i64)NC * LU;

    // --- weight prep ---
    make_wc_kernel<<<768, blk, 0, stream>>>(psi2_w, psi1_w, Wc32);
    make_cb_kernel<<<1, blk, 0, stream>>>(psi2_w, psi1_b, psi2_b, cb, tapb0);
    make_wstack<<<256, blk, 0, stream>>>(Wc32, Wstack);
    make_wvku<<<512, blk, 0, stream>>>(vk_w, phi_w, vk_b, phi_b, Wvku, bvku);
    cast_bf16<<<256, blk, 0, stream>>>(q_w, Qw);
    cast_bf16<<<512, blk, 0, stream>>>(vk_w, Wvk);

    // --- staging ---
    tcast_kernel<<<dim3(512, 4, 8), blk, 0, stream>>>(x_d, xd_t, xds_t, LD);
    mp_kernel<<<16384, blk, 0, stream>>>(x_d, mp);

    // conv3 (composed, K=768) + maxpool -> down2up transposed [l][c]
    gemm_bf16<1, 1><<<g128, blk, 0, stream>>>(Wstack, 0, 768, xd_t, (i64)LD * NC, 256,
                                              cb, 1.f, mp, tapb0, nullptr, d2u_t, 768, 1);

    // xd_t dead -> xu_t into R0
    tcast_kernel<<<dim3(256, 4, 8), blk, 0, stream>>>(x_u, xu_t, nullptr, LU);

    // vk on u2d path (composed weights): V half (transposed out), K half (natural out)
    gemm_bf16<0, 1><<<g128, blk, 0, stream>>>(Wvku, 0, 256, xu_t, act_bs, 256,
                                              bvku, 1.f, nullptr, nullptr, nullptr, v_u2d_t, 256, 1);
    gemm_bf16<0, 0><<<g128, blk, 0, stream>>>(Wvku + 65536, 0, 256, xu_t, act_bs, 256,
                                              bvku + 256, 1.f, nullptr, nullptr, nullptr, k_u2d, 256, 1);

    // qds = q_w @ pair-sum(x_d) + 2*q_b   (natural [c][j])
    gemm_bf16<0, 0><<<g128, blk, 0, stream>>>(Qw, 0, 256, xds_t, act_bs, 256,
                                              q_b, 2.f, nullptr, nullptr, nullptr, qds, 256, 1);

    // scores_u2d (split-K) + softmax -> attn1
    gemm_bf16<0, 2><<<gS, blk, 0, stream>>>(qds, cl_bs, LU, k_u2d, cl_bs, LU,
                                            nullptr, 0.f, nullptr, nullptr, nullptr, Sp, LU, SPLIT);
    softmax_bf16<<<NB * NC, blk, 0, stream>>>(Sp, attn1, SPLIT);

    // down_output = x_d + (attn1 @ v_u2d)[l>>1]   (fused expand-add)
    gemm_bf16<0, 4><<<g128, blk, 0, stream>>>(attn1, (i64)NC * NC, 256, v_u2d_t, act_bs, 256,
                                              nullptr, 0.f, nullptr, nullptr, x_d, out_dn, 256, 1);

    // vk on d2u path (PLAIN vk_w — no phi composition here!)
    gemm_bf16<0, 1><<<g128, blk, 0, stream>>>(Wvk, 0, 256, d2u_t, act_bs, 256,
                                              vk_b, 1.f, nullptr, nullptr, nullptr, v_d2u_t, 256, 1);
    gemm_bf16<0, 0><<<g128, blk, 0, stream>>>(Wvk + 65536, 0, 256, d2u_t, act_bs, 256,
                                              vk_b + 256, 1.f, nullptr, nullptr, nullptr, k_d2u, 256, 1);

    // q_u = q_w @ x_u + q_b  (natural [c][l])  -- overwrites d2u_t region (dead)
    gemm_bf16<0, 0><<<g128, blk, 0, stream>>>(Qw, 0, 256, xu_t, act_bs, 256,
                                              q_b, 1.f, nullptr, nullptr, nullptr, q_u, 256, 1);

    // scores_d2u + softmax -> attn2
    gemm_bf16<0, 2><<<gS, blk, 0, stream>>>(q_u, cl_bs, LU, k_d2u, cl_bs, LU,
                                            nullptr, 0.f, nullptr, nullptr, nullptr, Sp, LU, SPLIT);
    softmax_bf16<<<NB * NC, blk, 0, stream>>>(Sp, attn2, SPLIT);

    // up_output = x_u + attn2 @ v_d2u
    gemm_bf16<0, 3><<<g128, blk, 0, stream>>>(attn2, (i64)NC * NC, 256, v_d2u_t, act_bs, 256,
                                              nullptr, 0.f, nullptr, nullptr, x_u, out_up, 256, 1);
}

// Round 5
// 1118.687 us; speedup vs baseline: 3.3541x; 1.1030x over previous
//
#include <hip/hip_runtime.h>
#include <hip/hip_bf16.h>

#define NB 8
#define NC 256
#define LU 16384
#define LD 32768

typedef long long i64;
typedef unsigned short u16;
typedef __attribute__((ext_vector_type(8))) short bf16x8;
typedef __attribute__((ext_vector_type(4))) float f32x4;

__device__ __forceinline__ u16 f2b(float f) {
    __hip_bfloat16 h = __float2bfloat16(f);
    union { __hip_bfloat16 h; u16 u; } c;
    c.h = h;
    return c.u;
}
__device__ __forceinline__ float b2f(u16 u) {
    union { u16 u; __hip_bfloat16 h; } c;
    c.u = u;
    return __bfloat162float(c.h);
}
__device__ __forceinline__ uint4 bf16add8(uint4 a, uint4 b) {
    union { uint4 v; u16 u[8]; } x, y, r;
    x.v = a; y.v = b;
#pragma unroll
    for (int i = 0; i < 8; ++i) r.u[i] = f2b(b2f(x.u[i]) + b2f(y.u[i]));
    return r.v;
}

// ---------------------------------------------------------------------------
// Weight prep
// ---------------------------------------------------------------------------
__global__ __launch_bounds__(256) void make_wc_kernel(const float* __restrict__ psi2w,
                                                      const float* __restrict__ psi1w,
                                                      float* __restrict__ Wc) {
    int o = blockIdx.x & 255, tp = blockIdx.x >> 8;
    int c = threadIdx.x;
    float s = 0.f;
    for (int m = 0; m < NC; ++m)
        s += psi2w[(o * NC + m) * 3 + tp] * psi1w[m * NC + c];
    Wc[(tp * NC + o) * NC + c] = s;
}

__global__ __launch_bounds__(256) void make_cb_kernel(const float* __restrict__ psi2w,
                                                      const float* __restrict__ psi1b,
                                                      const float* __restrict__ psi2b,
                                                      float* __restrict__ cb,
                                                      float* __restrict__ tapb0) {
    int o = threadIdx.x;
    float full = psi2b[o];
    float t0 = 0.f;
    for (int tp = 0; tp < 3; ++tp) {
        float s = 0.f;
        for (int m = 0; m < NC; ++m) s += psi2w[(o * NC + m) * 3 + tp] * psi1b[m];
        full += s;
        if (tp == 0) t0 = s;
    }
    cb[o] = full;
    tapb0[o] = t0;
}

// Wstack[o][0..255]=Wc[1] (tap x[2j]), [256..511]=Wc[0] (x[2j-1]), [512..767]=Wc[2] (x[2j+1])
__global__ __launch_bounds__(256) void make_wstack(const float* __restrict__ Wc,
                                                   u16* __restrict__ Ws) {
    int o = blockIdx.x, c = threadIdx.x;
    Ws[(i64)o * 768 + 0 + c]   = f2b(Wc[(1 * NC + o) * NC + c]);
    Ws[(i64)o * 768 + 256 + c] = f2b(Wc[(0 * NC + o) * NC + c]);
    Ws[(i64)o * 768 + 512 + c] = f2b(Wc[(2 * NC + o) * NC + c]);
}

// W_vku = vk_w @ (I + phi)  (bf16, u2d path ONLY), bvku = vk_b + vk_w @ phi_b
__global__ __launch_bounds__(256) void make_wvku(const float* __restrict__ vkw,
                                                 const float* __restrict__ phiw,
                                                 const float* __restrict__ vkb,
                                                 const float* __restrict__ phib,
                                                 u16* __restrict__ Wvku,
                                                 float* __restrict__ bvku) {
    int o = blockIdx.x, c = threadIdx.x;
    float s = vkw[o * NC + c];
    float bs = 0.f;
    for (int m = 0; m < NC; ++m) {
        float w = vkw[o * NC + m];
        s += w * phiw[m * NC + c];
        bs += w * phib[m];
    }
    Wvku[(i64)o * NC + c] = f2b(s);
    if (c == 0) bvku[o] = vkb[o] + bs;
}

__global__ __launch_bounds__(256) void cast_bf16(const float* __restrict__ src,
                                                 u16* __restrict__ dst) {
    i64 i = (i64)blockIdx.x * 256 + threadIdx.x;
    dst[i] = f2b(src[i]);
}

// ---------------------------------------------------------------------------
// stage_xd: x_d fp32 [b][256][LD] -> xd_t bf16 [b][LD][256]  AND
//           maxpool3-s2 -> mp bf16 natural [b][256][LU]   (one pass over x_d)
// ---------------------------------------------------------------------------
__global__ __launch_bounds__(256) void stage_xd(const float* __restrict__ X,
                                                u16* __restrict__ Xt,
                                                u16* __restrict__ MPo) {
    const int l0 = blockIdx.x * 64;
    const int c0 = blockIdx.y * 64;
    const int b = blockIdx.z;
    const float* Xb = X + (i64)b * NC * LD;
    __shared__ float T[64][65];
    const int t = threadIdx.x;
    const int tc = t >> 4;
    const int tl = (t & 15) * 4;
#pragma unroll
    for (int p = 0; p < 4; ++p) {
        int c = c0 + p * 16 + tc;
        float4 v = *(const float4*)&Xb[(i64)c * LD + l0 + tl];
        T[tl + 0][p * 16 + tc] = v.x;
        T[tl + 1][p * 16 + tc] = v.y;
        T[tl + 2][p * 16 + tc] = v.z;
        T[tl + 3][p * 16 + tc] = v.w;
    }
    __syncthreads();
    {   // transposed bf16 write
        int lr = t >> 2, cq = (t & 3) * 16;
        union { u16 u[8]; uint4 v; } p0, p1;
#pragma unroll
        for (int i = 0; i < 8; ++i) p0.u[i] = f2b(T[lr][cq + i]);
#pragma unroll
        for (int i = 0; i < 8; ++i) p1.u[i] = f2b(T[lr][cq + 8 + i]);
        u16* Yb = Xt + (i64)b * LD * NC + (i64)(l0 + lr) * NC + c0 + cq;
        *(uint4*)Yb = p0.v;
        *(uint4*)(Yb + 8) = p1.v;
    }
    {   // maxpool: 32 j x 64 c per tile
        int c_loc = t >> 2, jq = (t & 3) * 8;
        int c_g = c0 + c_loc;
        float left = 0.f;
        if (jq == 0) left = (l0 > 0) ? Xb[(i64)c_g * LD + l0 - 1] : -INFINITY;
        union { u16 u[8]; uint4 q; } o;
#pragma unroll
        for (int j = 0; j < 8; ++j) {
            int jl = jq + j;
            float a = (jl == 0) ? left : T[2 * jl - 1][c_loc];
            o.u[j] = f2b(fmaxf(fmaxf(a, T[2 * jl][c_loc]), T[2 * jl + 1][c_loc]));
        }
        *(uint4*)&MPo[((i64)b * NC + c_g) * LU + (l0 >> 1) + jq] = o.q;
    }
}

// Transpose-cast x_u: fp32 [b][256][LU] -> bf16 [b][LU][256]
__global__ __launch_bounds__(256) void tcast_kernel(const float* __restrict__ X,
                                                    u16* __restrict__ Xt, int L) {
    const int l0 = blockIdx.x * 64;
    const int c0 = blockIdx.y * 64;
    const int b = blockIdx.z;
    const float* Xb = X + (i64)b * NC * L;
    __shared__ float T[64][65];
    const int t = threadIdx.x;
    const int tc = t >> 4;
    const int tl = (t & 15) * 4;
#pragma unroll
    for (int p = 0; p < 4; ++p) {
        int c = c0 + p * 16 + tc;
        float4 v = *(const float4*)&Xb[(i64)c * L + l0 + tl];
        T[tl + 0][p * 16 + tc] = v.x;
        T[tl + 1][p * 16 + tc] = v.y;
        T[tl + 2][p * 16 + tc] = v.z;
        T[tl + 3][p * 16 + tc] = v.w;
    }
    __syncthreads();
    int lr = t >> 2, cq = (t & 3) * 16;
    union { u16 u[8]; uint4 v; } p0, p1;
#pragma unroll
    for (int i = 0; i < 8; ++i) p0.u[i] = f2b(T[lr][cq + i]);
#pragma unroll
    for (int i = 0; i < 8; ++i) p1.u[i] = f2b(T[lr][cq + 8 + i]);
    u16* Yb = Xt + (i64)b * L * NC + (i64)(l0 + lr) * NC + c0 + cq;
    *(uint4*)Yb = p0.v;
    *(uint4*)(Yb + 8) = p1.v;
}

// ---------------------------------------------------------------------------
// bf16 MFMA GEMM, 256x128 tile, 512 threads (8 waves, wave-tile 64x64), BK=32.
// D[m][n] = sum_k A[m][k]*B[n][k]
// BSRC: 0 plain B [n][k] (ldb); 1 conv virtual K=768 over xd_t; 2 pair-sum
//       B[n][k] = xd_t[2n][k] + xd_t[2n+1][k]
// EPI : 0 bf16 natural [m][n]; 1 bf16 transposed [n][m] (+MP, -tapb0@n0);
//       2 fp32 split-K partials; 3 fp32 + RES; 4 fp32 expand-add + RES
// ---------------------------------------------------------------------------
template <int BSRC, int EPI>
__global__ __launch_bounds__(512) void gemm_bf16(
    const u16* __restrict__ A, i64 a_bs, int lda,
    const u16* __restrict__ B, i64 b_bs, int ldb,
    const float* __restrict__ bias, float bscale,
    const u16* __restrict__ MP, const float* __restrict__ TB0,
    const float* __restrict__ RES,
    void* __restrict__ Yv,
    int K, int split) {
    const int n0 = blockIdx.x * 128;
    const int m0 = blockIdx.y * 256;
    int b, k_beg, k_len, pidx;
    if (EPI == 2) {
        int s = blockIdx.z % split;
        b = blockIdx.z / split;
        k_len = K / split;
        k_beg = s * k_len;
        pidx = blockIdx.z;
    } else {
        b = blockIdx.z;
        k_beg = 0;
        k_len = K;
        pidx = 0;
    }

    const int t = threadIdx.x;
    const int lane = t & 63;
    const int wave = t >> 6;           // 0..7
    const int wm = wave >> 1;          // 0..3 (M)
    const int wn = wave & 1;           // 0..1 (N)
    const int srow_a = t >> 1;         // 0..255
    const int soff_a = (t & 1) * 16;
    const int srow_b = t >> 2;         // 0..127
    const int soff_b = (t & 3) * 8;

    __shared__ u16 As[256][32];
    __shared__ u16 Bs[128][32];

    f32x4 acc[4][4];
#pragma unroll
    for (int i = 0; i < 4; ++i)
#pragma unroll
        for (int j = 0; j < 4; ++j) acc[i][j] = (f32x4){0.f, 0.f, 0.f, 0.f};

    const u16* Ab = A + (i64)b * a_bs + (i64)(m0 + srow_a) * lda;
    const u16* Bb = B + (i64)b * b_bs;

    for (int k0 = k_beg; k0 < k_beg + k_len; k0 += 32) {
        uint4 av0 = *(const uint4*)(Ab + k0 + soff_a);
        uint4 av1 = *(const uint4*)(Ab + k0 + soff_a + 8);
        uint4 bv0;
        if (BSRC == 0) {
            bv0 = *(const uint4*)(Bb + (i64)(n0 + srow_b) * ldb + k0 + soff_b);
        } else if (BSRC == 1) {
            int kk = k0 + soff_b;      // 8-aligned, run stays in one 256-seg
            int seg = kk >> 8;
            int c = kk & 255;
            int l = 2 * (n0 + srow_b) + (seg == 0 ? 0 : (seg == 1 ? -1 : 1));
            bv0 = (l < 0) ? make_uint4(0u, 0u, 0u, 0u)
                          : *(const uint4*)(Bb + (i64)l * NC + c);
        } else {
            int kk = k0 + soff_b;
            i64 l = 2 * (i64)(n0 + srow_b);
            uint4 u0 = *(const uint4*)(Bb + l * NC + kk);
            uint4 u1 = *(const uint4*)(Bb + (l + 1) * NC + kk);
            bv0 = bf16add8(u0, u1);
        }
        __syncthreads();
        *(uint4*)&As[srow_a][soff_a] = av0;
        *(uint4*)&As[srow_a][soff_a + 8] = av1;
        *(uint4*)&Bs[srow_b][soff_b] = bv0;
        __syncthreads();
        bf16x8 af[4], bfr[4];
#pragma unroll
        for (int i = 0; i < 4; ++i) {
            af[i]  = *(const bf16x8*)&As[wm * 64 + i * 16 + (lane & 15)][(lane >> 4) * 8];
            bfr[i] = *(const bf16x8*)&Bs[wn * 64 + i * 16 + (lane & 15)][(lane >> 4) * 8];
        }
#pragma unroll
        for (int mi = 0; mi < 4; ++mi)
#pragma unroll
            for (int ni = 0; ni < 4; ++ni)
                acc[mi][ni] = __builtin_amdgcn_mfma_f32_16x16x32_bf16(af[mi], bfr[ni],
                                                                      acc[mi][ni], 0, 0, 0);
    }

    const int mb0 = m0 + wm * 64 + ((lane >> 4) << 2);
    const int nb0 = n0 + wn * 64 + (lane & 15);

#pragma unroll
    for (int mi = 0; mi < 4; ++mi) {
#pragma unroll
        for (int ni = 0; ni < 4; ++ni) {
            int n_g = nb0 + ni * 16;
            if (EPI == 0) {
                u16* Y = (u16*)Yv + (i64)b * NC * LU;
#pragma unroll
                for (int r = 0; r < 4; ++r) {
                    int m_g = mb0 + mi * 16 + r;
                    float v = acc[mi][ni][r];
                    if (bias) v += bscale * bias[m_g];
                    Y[(i64)m_g * LU + n_g] = f2b(v);
                }
            } else if (EPI == 1) {
                u16* Y = (u16*)Yv + (i64)b * LU * NC;
                int mbase = mb0 + mi * 16;
                float vv[4];
#pragma unroll
                for (int r = 0; r < 4; ++r) {
                    int m_g = mbase + r;
                    float v = acc[mi][ni][r];
                    if (bias) v += bscale * bias[m_g];
                    if (MP) v += b2f(MP[(i64)b * NC * LU + (i64)m_g * LU + n_g]);
                    if (TB0 && n_g == 0) v -= TB0[m_g];
                    vv[r] = v;
                }
                ushort4 pk;
                pk.x = f2b(vv[0]); pk.y = f2b(vv[1]); pk.z = f2b(vv[2]); pk.w = f2b(vv[3]);
                *(ushort4*)&Y[(i64)n_g * NC + mbase] = pk;
            } else if (EPI == 2) {
                float* Y = (float*)Yv + (i64)pidx * NC * NC;
#pragma unroll
                for (int r = 0; r < 4; ++r) {
                    int m_g = mb0 + mi * 16 + r;
                    Y[(i64)m_g * NC + n_g] = acc[mi][ni][r];
                }
            } else if (EPI == 3) {
                float* Y = (float*)Yv + (i64)b * NC * LU;
                const float* R = RES + (i64)b * NC * LU;
#pragma unroll
                for (int r = 0; r < 4; ++r) {
                    int m_g = mb0 + mi * 16 + r;
                    i64 idx = (i64)m_g * LU + n_g;
                    Y[idx] = acc[mi][ni][r] + R[idx];
                }
            } else {
                float* Y = (float*)Yv + (i64)b * NC * LD;
                const float* R = RES + (i64)b * NC * LD;
#pragma unroll
                for (int r = 0; r < 4; ++r) {
                    int m_g = mb0 + mi * 16 + r;
                    i64 idx = (i64)m_g * LD + 2 * (i64)n_g;
                    float vlo = acc[mi][ni][r] + R[idx];
                    float vhi = acc[mi][ni][r] + R[idx + 1];
                    *(float2*)&Y[idx] = make_float2(vlo, vhi);
                }
            }
        }
    }
}

// Reduce split-K partials, scale 1/16, softmax over d, write bf16 attn[b][c][d].
__global__ __launch_bounds__(256) void softmax_bf16(const float* __restrict__ Sp,
                                                    u16* __restrict__ Attn, int split) {
    int bc = blockIdx.x;
    int b = bc >> 8, c = bc & 255;
    int d = threadIdx.x;
    float v = 0.f;
    for (int s = 0; s < split; ++s)
        v += Sp[((i64)(b * split + s) * NC + c) * NC + d];
    v *= (1.0f / 16.0f);
    __shared__ float red[256];
    red[d] = v;
    __syncthreads();
    for (int off = 128; off; off >>= 1) {
        if (d < off) red[d] = fmaxf(red[d], red[d + off]);
        __syncthreads();
    }
    float mx = red[0];
    __syncthreads();
    float e = expf(v - mx);
    red[d] = e;
    __syncthreads();
    for (int off = 128; off; off >>= 1) {
        if (d < off) red[d] += red[d + off];
        __syncthreads();
    }
    float inv = 1.f / red[0];
    Attn[((i64)b * NC + c) * NC + d] = f2b(e * inv);
}

// ---------------------------------------------------------------------------
extern "C" void kernel_launch(void* const* d_in, const int* in_sizes, int n_in,
                              void* d_out, int out_size, void* d_ws, size_t ws_size,
                              hipStream_t stream) {
    const float* x_u = (const float*)d_in[0];
    const float* x_d = (const float*)d_in[1];
    const float* vk_w = (const float*)d_in[2];
    const float* vk_b = (const float*)d_in[3];
    const float* q_w = (const float*)d_in[4];
    const float* q_b = (const float*)d_in[5];
    const float* psi1_w = (const float*)d_in[6];
    const float* psi1_b = (const float*)d_in[7];
    const float* psi2_w = (const float*)d_in[8];
    const float* psi2_b = (const float*)d_in[9];
    const float* phi_w = (const float*)d_in[10];
    const float* phi_b = (const float*)d_in[11];

    const i64 UNIT = 67108864;  // 64 MiB
    char* ws = (char*)d_ws;

    u16* xd_t    = (u16*)(ws);             // [0,2U) alive through qds GEMM
    u16* xu_t    = (u16*)(ws);             // R0 (after xd_t dead)
    u16* v_u2d_t = (u16*)(ws + UNIT);      // R1 (after xd_t dead), dead after PVdown
    u16* k_d2u   = (u16*)(ws + UNIT);      // R1 reuse
    u16* v_d2u_t = (u16*)(ws + 2 * UNIT);  // R2
    u16* mp      = (u16*)(ws + 3 * UNIT);  // R3, dead after conv3
    u16* k_u2d   = (u16*)(ws + 3 * UNIT);  // R3 reuse
    u16* d2u_t   = (u16*)(ws + 4 * UNIT);  // R4, dead after vk_d2u
    u16* q_u     = (u16*)(ws + 4 * UNIT);  // R4 reuse

    char* sm = ws + 5 * UNIT;
    float* Wc32  = (float*)sm; sm += 786432;
    float* cb    = (float*)sm; sm += 1024;
    float* tapb0 = (float*)sm; sm += 1024;
    u16* Wstack  = (u16*)sm;   sm += 393216;
    u16* Wvku    = (u16*)sm;   sm += 262144;   // composed vk@(I+phi): u2d ONLY
    float* bvku  = (float*)sm; sm += 2048;
    u16* Qw      = (u16*)sm;   sm += 131072;
    u16* Wvk     = (u16*)sm;   sm += 262144;   // plain vk_w: d2u path
    u16* attn1   = (u16*)sm;   sm += 1048576;
    u16* attn2   = (u16*)sm;   sm += 1048576;

    float* out_up = (float*)d_out;
    float* out_dn = out_up + (i64)NB * NC * LU;
    float* Sp  = (float*)d_out;                    // partials alias out_up
    u16* qds   = (u16*)((char*)d_out + 2 * UNIT);  // alias out_dn head

    const int SPLIT = 16;
    dim3 blk(256);
    dim3 blk5(512);
    dim3 gAct(128, 1, 8);       // N=LU tiles of 128, O=256
    dim3 gS(2, 1, 8 * SPLIT);   // scores: N=256 -> 2 n-blocks
    const i64 act_bs = (i64)LU * NC;
    const i64 cl_bs  = (i64)NC * LU;

    // --- weight prep ---
    make_wc_kernel<<<768, blk, 0, stream>>>(psi2_w, psi1_w, Wc32);
    make_cb_kernel<<<1, blk, 0, stream>>>(psi2_w, psi1_b, psi2_b, cb, tapb0);
    make_wstack<<<256, blk, 0, stream>>>(Wc32, Wstack);
    make_wvku<<<512, blk, 0, stream>>>(vk_w, phi_w, vk_b, phi_b, Wvku, bvku);
    cast_bf16<<<256, blk, 0, stream>>>(q_w, Qw);
    cast_bf16<<<512, blk, 0, stream>>>(vk_w, Wvk);

    // --- stage x_d (transpose-cast + fused maxpool, one pass) ---
    stage_xd<<<dim3(512, 4, 8), blk, 0, stream>>>(x_d, xd_t, mp);

    // conv3 (composed, K=768) + maxpool -> down2up transposed [l][c]
    gemm_bf16<1, 1><<<gAct, blk5, 0, stream>>>(Wstack, 0, 768, xd_t, (i64)LD * NC, 256,
                                               cb, 1.f, mp, tapb0, nullptr, d2u_t, 768, 1);

    // qds = q_w @ (xd[2j]+xd[2j+1]) + 2*q_b  (pair-sum staging from xd_t)
    gemm_bf16<2, 0><<<gAct, blk5, 0, stream>>>(Qw, 0, 256, xd_t, (i64)LD * NC, 256,
                                               q_b, 2.f, nullptr, nullptr, nullptr, qds, 256, 1);

    // xd_t now dead -> xu_t into R0
    tcast_kernel<<<dim3(256, 4, 8), blk, 0, stream>>>(x_u, xu_t, LU);

    // vk on u2d path (composed): V half transposed out, K half natural out
    gemm_bf16<0, 1><<<gAct, blk5, 0, stream>>>(Wvku, 0, 256, xu_t, act_bs, 256,
                                               bvku, 1.f, nullptr, nullptr, nullptr, v_u2d_t, 256, 1);
    gemm_bf16<0, 0><<<gAct, blk5, 0, stream>>>(Wvku + 65536, 0, 256, xu_t, act_bs, 256,
                                               bvku + 256, 1.f, nullptr, nullptr, nullptr, k_u2d, 256, 1);

    // scores_u2d (split-K) + softmax -> attn1
    gemm_bf16<0, 2><<<gS, blk5, 0, stream>>>(qds, cl_bs, LU, k_u2d, cl_bs, LU,
                                             nullptr, 0.f, nullptr, nullptr, nullptr, Sp, LU, SPLIT);
    softmax_bf16<<<NB * NC, blk, 0, stream>>>(Sp, attn1, SPLIT);

    // down_output = x_d + (attn1 @ v_u2d)[l>>1]   (fused expand-add)
    gemm_bf16<0, 4><<<gAct, blk5, 0, stream>>>(attn1, (i64)NC * NC, 256, v_u2d_t, act_bs, 256,
                                               nullptr, 0.f, nullptr, nullptr, x_d, out_dn, 256, 1);

    // vk on d2u path (PLAIN vk_w)
    gemm_bf16<0, 1><<<gAct, blk5, 0, stream>>>(Wvk, 0, 256, d2u_t, act_bs, 256,
                                               vk_b, 1.f, nullptr, nullptr, nullptr, v_d2u_t, 256, 1);
    gemm_bf16<0, 0><<<gAct, blk5, 0, stream>>>(Wvk + 65536, 0, 256, d2u_t, act_bs, 256,
                                               vk_b + 256, 1.f, nullptr, nullptr, nullptr, k_d2u, 256, 1);

    // q_u = q_w @ x_u + q_b  (natural [c][l]) -- overwrites d2u_t region (dead)
    gemm_bf16<0, 0><<<gAct, blk5, 0, stream>>>(Qw, 0, 256, xu_t, act_bs, 256,
                                               q_b, 1.f, nullptr, nullptr, nullptr, q_u, 256, 1);

    // scores_d2u + softmax -> attn2
    gemm_bf16<0, 2><<<gS, blk5, 0, stream>>>(q_u, cl_bs, LU, k_d2u, cl_bs, LU,
                                             nullptr, 0.f, nullptr, nullptr, nullptr, Sp, LU, SPLIT);
    softmax_bf16<<<NB * NC, blk, 0, stream>>>(Sp, attn2, SPLIT);

    // up_output = x_u + attn2 @ v_d2u
    gemm_bf16<0, 3><<<gAct, blk5, 0, stream>>>(attn2, (i64)NC * NC, 256, v_d2u_t, act_bs, 256,
                                               nullptr, 0.f, nullptr, nullptr, x_u, out_up, 256, 1);
}

// Round 6
// 1111.400 us; speedup vs baseline: 3.3761x; 1.0066x over previous
//
#include <hip/hip_runtime.h>
#include <hip/hip_bf16.h>

#define NB 8
#define NC 256
#define LU 16384
#define LD 32768

typedef long long i64;
typedef unsigned short u16;
typedef __attribute__((ext_vector_type(8))) short bf16x8;
typedef __attribute__((ext_vector_type(4))) float f32x4;

__device__ __forceinline__ u16 f2b(float f) {
    __hip_bfloat16 h = __float2bfloat16(f);
    union { __hip_bfloat16 h; u16 u; } c;
    c.h = h;
    return c.u;
}
__device__ __forceinline__ float b2f(u16 u) {
    union { u16 u; __hip_bfloat16 h; } c;
    c.u = u;
    return __bfloat162float(c.h);
}
__device__ __forceinline__ uint4 bf16add8(uint4 a, uint4 b) {
    union { uint4 v; u16 u[8]; } x, y, r;
    x.v = a; y.v = b;
#pragma unroll
    for (int i = 0; i < 8; ++i) r.u[i] = f2b(b2f(x.u[i]) + b2f(y.u[i]));
    return r.v;
}
// async global->LDS DMA, 16B per lane; lds dest = wave-uniform base + lane*16
__device__ __forceinline__ void gl16(const u16* g, u16* l) {
    __builtin_amdgcn_global_load_lds(
        (const __attribute__((address_space(1))) void*)g,
        (__attribute__((address_space(3))) void*)l, 16, 0, 0);
}

// ---------------------------------------------------------------------------
// Weight prep
// ---------------------------------------------------------------------------
__global__ __launch_bounds__(256) void make_wc_kernel(const float* __restrict__ psi2w,
                                                      const float* __restrict__ psi1w,
                                                      float* __restrict__ Wc) {
    int o = blockIdx.x & 255, tp = blockIdx.x >> 8;
    int c = threadIdx.x;
    float s = 0.f;
    for (int m = 0; m < NC; ++m)
        s += psi2w[(o * NC + m) * 3 + tp] * psi1w[m * NC + c];
    Wc[(tp * NC + o) * NC + c] = s;
}

__global__ __launch_bounds__(256) void make_cb_kernel(const float* __restrict__ psi2w,
                                                      const float* __restrict__ psi1b,
                                                      const float* __restrict__ psi2b,
                                                      float* __restrict__ cb,
                                                      float* __restrict__ tapb0) {
    int o = threadIdx.x;
    float full = psi2b[o];
    float t0 = 0.f;
    for (int tp = 0; tp < 3; ++tp) {
        float s = 0.f;
        for (int m = 0; m < NC; ++m) s += psi2w[(o * NC + m) * 3 + tp] * psi1b[m];
        full += s;
        if (tp == 0) t0 = s;
    }
    cb[o] = full;
    tapb0[o] = t0;
}

// Wstack[o][0..255]=Wc[1] (tap x[2j]), [256..511]=Wc[0] (x[2j-1]), [512..767]=Wc[2] (x[2j+1])
__global__ __launch_bounds__(256) void make_wstack(const float* __restrict__ Wc,
                                                   u16* __restrict__ Ws) {
    int o = blockIdx.x, c = threadIdx.x;
    Ws[(i64)o * 768 + 0 + c]   = f2b(Wc[(1 * NC + o) * NC + c]);
    Ws[(i64)o * 768 + 256 + c] = f2b(Wc[(0 * NC + o) * NC + c]);
    Ws[(i64)o * 768 + 512 + c] = f2b(Wc[(2 * NC + o) * NC + c]);
}

// W_vku = vk_w @ (I + phi)  (bf16, u2d path ONLY), bvku = vk_b + vk_w @ phi_b
__global__ __launch_bounds__(256) void make_wvku(const float* __restrict__ vkw,
                                                 const float* __restrict__ phiw,
                                                 const float* __restrict__ vkb,
                                                 const float* __restrict__ phib,
                                                 u16* __restrict__ Wvku,
                                                 float* __restrict__ bvku) {
    int o = blockIdx.x, c = threadIdx.x;
    float s = vkw[o * NC + c];
    float bs = 0.f;
    for (int m = 0; m < NC; ++m) {
        float w = vkw[o * NC + m];
        s += w * phiw[m * NC + c];
        bs += w * phib[m];
    }
    Wvku[(i64)o * NC + c] = f2b(s);
    if (c == 0) bvku[o] = vkb[o] + bs;
}

__global__ __launch_bounds__(256) void cast_bf16(const float* __restrict__ src,
                                                 u16* __restrict__ dst) {
    i64 i = (i64)blockIdx.x * 256 + threadIdx.x;
    dst[i] = f2b(src[i]);
}

__global__ __launch_bounds__(64) void zero_fill(u16* __restrict__ z) {
    z[threadIdx.x] = 0;
}

// ---------------------------------------------------------------------------
// stage_xd: x_d fp32 [b][256][LD] -> xd_t bf16 [b][LD][256]  AND
//           maxpool3-s2 -> mp bf16 natural [b][256][LU]   (one pass over x_d)
// ---------------------------------------------------------------------------
__global__ __launch_bounds__(256) void stage_xd(const float* __restrict__ X,
                                                u16* __restrict__ Xt,
                                                u16* __restrict__ MPo) {
    const int l0 = blockIdx.x * 64;
    const int c0 = blockIdx.y * 64;
    const int b = blockIdx.z;
    const float* Xb = X + (i64)b * NC * LD;
    __shared__ float T[64][65];
    const int t = threadIdx.x;
    const int tc = t >> 4;
    const int tl = (t & 15) * 4;
#pragma unroll
    for (int p = 0; p < 4; ++p) {
        int c = c0 + p * 16 + tc;
        float4 v = *(const float4*)&Xb[(i64)c * LD + l0 + tl];
        T[tl + 0][p * 16 + tc] = v.x;
        T[tl + 1][p * 16 + tc] = v.y;
        T[tl + 2][p * 16 + tc] = v.z;
        T[tl + 3][p * 16 + tc] = v.w;
    }
    __syncthreads();
    {   // transposed bf16 write
        int lr = t >> 2, cq = (t & 3) * 16;
        union { u16 u[8]; uint4 v; } p0, p1;
#pragma unroll
        for (int i = 0; i < 8; ++i) p0.u[i] = f2b(T[lr][cq + i]);
#pragma unroll
        for (int i = 0; i < 8; ++i) p1.u[i] = f2b(T[lr][cq + 8 + i]);
        u16* Yb = Xt + (i64)b * LD * NC + (i64)(l0 + lr) * NC + c0 + cq;
        *(uint4*)Yb = p0.v;
        *(uint4*)(Yb + 8) = p1.v;
    }
    {   // maxpool: 32 j x 64 c per tile
        int c_loc = t >> 2, jq = (t & 3) * 8;
        int c_g = c0 + c_loc;
        float left = 0.f;
        if (jq == 0) left = (l0 > 0) ? Xb[(i64)c_g * LD + l0 - 1] : -INFINITY;
        union { u16 u[8]; uint4 q; } o;
#pragma unroll
        for (int j = 0; j < 8; ++j) {
            int jl = jq + j;
            float a = (jl == 0) ? left : T[2 * jl - 1][c_loc];
            o.u[j] = f2b(fmaxf(fmaxf(a, T[2 * jl][c_loc]), T[2 * jl + 1][c_loc]));
        }
        *(uint4*)&MPo[((i64)b * NC + c_g) * LU + (l0 >> 1) + jq] = o.q;
    }
}

// Transpose-cast x_u: fp32 [b][256][LU] -> bf16 [b][LU][256]
__global__ __launch_bounds__(256) void tcast_kernel(const float* __restrict__ X,
                                                    u16* __restrict__ Xt, int L) {
    const int l0 = blockIdx.x * 64;
    const int c0 = blockIdx.y * 64;
    const int b = blockIdx.z;
    const float* Xb = X + (i64)b * NC * L;
    __shared__ float T[64][65];
    const int t = threadIdx.x;
    const int tc = t >> 4;
    const int tl = (t & 15) * 4;
#pragma unroll
    for (int p = 0; p < 4; ++p) {
        int c = c0 + p * 16 + tc;
        float4 v = *(const float4*)&Xb[(i64)c * L + l0 + tl];
        T[tl + 0][p * 16 + tc] = v.x;
        T[tl + 1][p * 16 + tc] = v.y;
        T[tl + 2][p * 16 + tc] = v.z;
        T[tl + 3][p * 16 + tc] = v.w;
    }
    __syncthreads();
    int lr = t >> 2, cq = (t & 3) * 16;
    union { u16 u[8]; uint4 v; } p0, p1;
#pragma unroll
    for (int i = 0; i < 8; ++i) p0.u[i] = f2b(T[lr][cq + i]);
#pragma unroll
    for (int i = 0; i < 8; ++i) p1.u[i] = f2b(T[lr][cq + 8 + i]);
    u16* Yb = Xt + (i64)b * L * NC + (i64)(l0 + lr) * NC + c0 + cq;
    *(uint4*)Yb = p0.v;
    *(uint4*)(Yb + 8) = p1.v;
}

// ---------------------------------------------------------------------------
// bf16 MFMA GEMM, 256x128 tile, 512 threads (8 waves, wave-tile 64x64), BK=32.
// Staging via global_load_lds (16B/lane) with source-pre-swizzled LDS layout:
//   LDS slot s of row r holds global chunk s ^ ((r>>1)&3)  (chunks of 8 u16).
// BSRC: 0 plain B [n][k] (ldb); 1 conv virtual K=768 over xd_t; 2 pair-sum
//       B[n][k] = xd_t[2n][k] + xd_t[2n+1][k]  (reg-staged, swizzled ds_write)
// EPI : 0 bf16 natural [m][n]; 1 bf16 transposed [n][m] (+MP, -tapb0@n0);
//       2 fp32 split-K partials; 3 fp32 + RES; 4 fp32 expand-add + RES
// ---------------------------------------------------------------------------
template <int BSRC, int EPI>
__global__ __launch_bounds__(512) void gemm_bf16(
    const u16* __restrict__ A, i64 a_bs, int lda,
    const u16* __restrict__ B, i64 b_bs, int ldb,
    const float* __restrict__ bias, float bscale,
    const u16* __restrict__ MP, const float* __restrict__ TB0,
    const float* __restrict__ RES, const u16* __restrict__ zbuf,
    void* __restrict__ Yv,
    int K, int split) {
    const int n0 = blockIdx.x * 128;
    const int m0 = blockIdx.y * 256;
    int b, k_beg, k_len, pidx;
    if (EPI == 2) {
        int s = blockIdx.z % split;
        b = blockIdx.z / split;
        k_len = K / split;
        k_beg = s * k_len;
        pidx = blockIdx.z;
    } else {
        b = blockIdx.z;
        k_beg = 0;
        k_len = K;
        pidx = 0;
    }

    const int t = threadIdx.x;
    const int lane = t & 63;
    const int wave = t >> 6;           // 0..7
    const int wm = wave >> 1;          // 0..3 (M)
    const int wn = wave & 1;           // 0..1 (N)

    __shared__ u16 As[256 * 32];
    __shared__ u16 Bs[128 * 32];

    f32x4 acc[4][4];
#pragma unroll
    for (int i = 0; i < 4; ++i)
#pragma unroll
        for (int j = 0; j < 4; ++j) acc[i][j] = (f32x4){0.f, 0.f, 0.f, 0.f};

    // ---- staging geometry (per-lane constants) ----
    // A: wave covers rows [wave*32, wave*32+32) in two 16-row DMA calls.
    const int ra = wave * 32 + (lane >> 2);
    const int ca = (lane & 3) ^ ((ra >> 1) & 3);
    const u16* Abase0 = A + (i64)b * a_bs + (i64)(m0 + ra) * lda + ca * 8 + k_beg;
    const u16* Abase1 = Abase0 + (i64)16 * lda;   // swizzle identical (+16 rows)
    u16* AsDst0 = &As[(wave * 32) * 32];
    u16* AsDst1 = &As[(wave * 32 + 16) * 32];
    // B: wave covers rows [wave*16, wave*16+16) in one DMA call.
    const int rb = wave * 16 + (lane >> 2);
    const int cb_ = (lane & 3) ^ ((rb >> 1) & 3);
    u16* BsDst = &Bs[(wave * 16) * 32];
    const u16* Bb = B + (i64)b * b_bs;
    const u16* Bbase0 = Bb + (i64)(n0 + rb) * ldb + cb_ * 8 + k_beg;
    // BSRC2 reg-stage geometry: thread -> one 8-elem chunk
    const int r2 = t >> 2;
    const int sl2 = (t & 3) ^ ((r2 >> 1) & 3);
    // frag read slot (lane-constant swizzle)
    const int fslot = (((lane >> 4) ^ ((lane >> 1) & 3))) * 8;

    for (int k0 = 0; k0 < k_len; k0 += 32) {
        gl16(Abase0 + k0, AsDst0);
        gl16(Abase1 + k0, AsDst1);
        if (BSRC == 0) {
            gl16(Bbase0 + k0, BsDst);
        } else if (BSRC == 1) {
            int kk = k0 + cb_ * 8;          // virtual k, 8-aligned in one seg
            int seg = kk >> 8;
            int c = kk & 255;
            int l = 2 * (n0 + rb) + (seg == 0 ? 0 : (seg == 1 ? -1 : 1));
            const u16* src = (l < 0) ? zbuf : Bb + (i64)l * NC + c;
            gl16(src, BsDst);
        } else {
            int kk = k0 + (t & 3) * 8;
            i64 l = 2 * (i64)(n0 + r2);
            uint4 u0 = *(const uint4*)(Bb + l * NC + kk);
            uint4 u1 = *(const uint4*)(Bb + (l + 1) * NC + kk);
            uint4 sv = bf16add8(u0, u1);
            *(uint4*)&Bs[r2 * 32 + sl2 * 8] = sv;
        }
        __syncthreads();   // drains DMA (vmcnt) + ds_write (lgkm)
        bf16x8 af[4], bfr[4];
#pragma unroll
        for (int i = 0; i < 4; ++i) {
            af[i]  = *(const bf16x8*)&As[(wm * 64 + i * 16 + (lane & 15)) * 32 + fslot];
            bfr[i] = *(const bf16x8*)&Bs[(wn * 64 + i * 16 + (lane & 15)) * 32 + fslot];
        }
#pragma unroll
        for (int mi = 0; mi < 4; ++mi)
#pragma unroll
            for (int ni = 0; ni < 4; ++ni)
                acc[mi][ni] = __builtin_amdgcn_mfma_f32_16x16x32_bf16(af[mi], bfr[ni],
                                                                      acc[mi][ni], 0, 0, 0);
        __syncthreads();
    }

    const int mb0 = m0 + wm * 64 + ((lane >> 4) << 2);
    const int nb0 = n0 + wn * 64 + (lane & 15);

#pragma unroll
    for (int mi = 0; mi < 4; ++mi) {
#pragma unroll
        for (int ni = 0; ni < 4; ++ni) {
            int n_g = nb0 + ni * 16;
            if (EPI == 0) {
                u16* Y = (u16*)Yv + (i64)b * NC * LU;
#pragma unroll
                for (int r = 0; r < 4; ++r) {
                    int m_g = mb0 + mi * 16 + r;
                    float v = acc[mi][ni][r];
                    if (bias) v += bscale * bias[m_g];
                    Y[(i64)m_g * LU + n_g] = f2b(v);
                }
            } else if (EPI == 1) {
                u16* Y = (u16*)Yv + (i64)b * LU * NC;
                int mbase = mb0 + mi * 16;
                float vv[4];
#pragma unroll
                for (int r = 0; r < 4; ++r) {
                    int m_g = mbase + r;
                    float v = acc[mi][ni][r];
                    if (bias) v += bscale * bias[m_g];
                    if (MP) v += b2f(MP[(i64)b * NC * LU + (i64)m_g * LU + n_g]);
                    if (TB0 && n_g == 0) v -= TB0[m_g];
                    vv[r] = v;
                }
                ushort4 pk;
                pk.x = f2b(vv[0]); pk.y = f2b(vv[1]); pk.z = f2b(vv[2]); pk.w = f2b(vv[3]);
                *(ushort4*)&Y[(i64)n_g * NC + mbase] = pk;
            } else if (EPI == 2) {
                float* Y = (float*)Yv + (i64)pidx * NC * NC;
#pragma unroll
                for (int r = 0; r < 4; ++r) {
                    int m_g = mb0 + mi * 16 + r;
                    Y[(i64)m_g * NC + n_g] = acc[mi][ni][r];
                }
            } else if (EPI == 3) {
                float* Y = (float*)Yv + (i64)b * NC * LU;
                const float* R = RES + (i64)b * NC * LU;
#pragma unroll
                for (int r = 0; r < 4; ++r) {
                    int m_g = mb0 + mi * 16 + r;
                    i64 idx = (i64)m_g * LU + n_g;
                    Y[idx] = acc[mi][ni][r] + R[idx];
                }
            } else {
                float* Y = (float*)Yv + (i64)b * NC * LD;
                const float* R = RES + (i64)b * NC * LD;
#pragma unroll
                for (int r = 0; r < 4; ++r) {
                    int m_g = mb0 + mi * 16 + r;
                    i64 idx = (i64)m_g * LD + 2 * (i64)n_g;
                    float vlo = acc[mi][ni][r] + R[idx];
                    float vhi = acc[mi][ni][r] + R[idx + 1];
                    *(float2*)&Y[idx] = make_float2(vlo, vhi);
                }
            }
        }
    }
}

// Reduce split-K partials, scale 1/16, softmax over d, write bf16 attn[b][c][d].
__global__ __launch_bounds__(256) void softmax_bf16(const float* __restrict__ Sp,
                                                    u16* __restrict__ Attn, int split) {
    int bc = blockIdx.x;
    int b = bc >> 8, c = bc & 255;
    int d = threadIdx.x;
    float v = 0.f;
    for (int s = 0; s < split; ++s)
        v += Sp[((i64)(b * split + s) * NC + c) * NC + d];
    v *= (1.0f / 16.0f);
    __shared__ float red[256];
    red[d] = v;
    __syncthreads();
    for (int off = 128; off; off >>= 1) {
        if (d < off) red[d] = fmaxf(red[d], red[d + off]);
        __syncthreads();
    }
    float mx = red[0];
    __syncthreads();
    float e = expf(v - mx);
    red[d] = e;
    __syncthreads();
    for (int off = 128; off; off >>= 1) {
        if (d < off) red[d] += red[d + off];
        __syncthreads();
    }
    float inv = 1.f / red[0];
    Attn[((i64)b * NC + c) * NC + d] = f2b(e * inv);
}

// ---------------------------------------------------------------------------
extern "C" void kernel_launch(void* const* d_in, const int* in_sizes, int n_in,
                              void* d_out, int out_size, void* d_ws, size_t ws_size,
                              hipStream_t stream) {
    const float* x_u = (const float*)d_in[0];
    const float* x_d = (const float*)d_in[1];
    const float* vk_w = (const float*)d_in[2];
    const float* vk_b = (const float*)d_in[3];
    const float* q_w = (const float*)d_in[4];
    const float* q_b = (const float*)d_in[5];
    const float* psi1_w = (const float*)d_in[6];
    const float* psi1_b = (const float*)d_in[7];
    const float* psi2_w = (const float*)d_in[8];
    const float* psi2_b = (const float*)d_in[9];
    const float* phi_w = (const float*)d_in[10];
    const float* phi_b = (const float*)d_in[11];

    const i64 UNIT = 67108864;  // 64 MiB
    char* ws = (char*)d_ws;

    u16* xd_t    = (u16*)(ws);             // [0,2U) alive through qds GEMM
    u16* xu_t    = (u16*)(ws);             // R0 (after xd_t dead)
    u16* v_u2d_t = (u16*)(ws + UNIT);      // R1 (after xd_t dead), dead after PVdown
    u16* k_d2u   = (u16*)(ws + UNIT);      // R1 reuse
    u16* v_d2u_t = (u16*)(ws + 2 * UNIT);  // R2
    u16* mp      = (u16*)(ws + 3 * UNIT);  // R3, dead after conv3
    u16* k_u2d   = (u16*)(ws + 3 * UNIT);  // R3 reuse
    u16* d2u_t   = (u16*)(ws + 4 * UNIT);  // R4, dead after vk_d2u
    u16* q_u     = (u16*)(ws + 4 * UNIT);  // R4 reuse

    char* sm = ws + 5 * UNIT;
    float* Wc32  = (float*)sm; sm += 786432;
    float* cb    = (float*)sm; sm += 1024;
    float* tapb0 = (float*)sm; sm += 1024;
    u16* Wstack  = (u16*)sm;   sm += 393216;
    u16* Wvku    = (u16*)sm;   sm += 262144;   // composed vk@(I+phi): u2d ONLY
    float* bvku  = (float*)sm; sm += 2048;
    u16* Qw      = (u16*)sm;   sm += 131072;
    u16* Wvk     = (u16*)sm;   sm += 262144;   // plain vk_w: d2u path
    u16* attn1   = (u16*)sm;   sm += 1048576;
    u16* attn2   = (u16*)sm;   sm += 1048576;
    u16* zbuf    = (u16*)sm;   sm += 256;      // zeros page for conv boundary

    float* out_up = (float*)d_out;
    float* out_dn = out_up + (i64)NB * NC * LU;
    float* Sp  = (float*)d_out;                    // partials alias out_up
    u16* qds   = (u16*)((char*)d_out + 2 * UNIT);  // alias out_dn head

    const int SPLIT = 16;
    dim3 blk(256);
    dim3 blk5(512);
    dim3 gAct(128, 1, 8);       // N=LU tiles of 128, O=256
    dim3 gS(2, 1, 8 * SPLIT);   // scores: N=256 -> 2 n-blocks
    const i64 act_bs = (i64)LU * NC;
    const i64 cl_bs  = (i64)NC * LU;

    // --- weight prep ---
    make_wc_kernel<<<768, blk, 0, stream>>>(psi2_w, psi1_w, Wc32);
    make_cb_kernel<<<1, blk, 0, stream>>>(psi2_w, psi1_b, psi2_b, cb, tapb0);
    make_wstack<<<256, blk, 0, stream>>>(Wc32, Wstack);
    make_wvku<<<512, blk, 0, stream>>>(vk_w, phi_w, vk_b, phi_b, Wvku, bvku);
    cast_bf16<<<256, blk, 0, stream>>>(q_w, Qw);
    cast_bf16<<<512, blk, 0, stream>>>(vk_w, Wvk);
    zero_fill<<<1, 64, 0, stream>>>(zbuf);

    // --- stage x_d (transpose-cast + fused maxpool, one pass) ---
    stage_xd<<<dim3(512, 4, 8), blk, 0, stream>>>(x_d, xd_t, mp);

    // conv3 (composed, K=768) + maxpool -> down2up transposed [l][c]
    gemm_bf16<1, 1><<<gAct, blk5, 0, stream>>>(Wstack, 0, 768, xd_t, (i64)LD * NC, 256,
                                               cb, 1.f, mp, tapb0, nullptr, zbuf, d2u_t, 768, 1);

    // qds = q_w @ (xd[2j]+xd[2j+1]) + 2*q_b  (pair-sum staging from xd_t)
    gemm_bf16<2, 0><<<gAct, blk5, 0, stream>>>(Qw, 0, 256, xd_t, (i64)LD * NC, 256,
                                               q_b, 2.f, nullptr, nullptr, nullptr, zbuf, qds, 256, 1);

    // xd_t now dead -> xu_t into R0
    tcast_kernel<<<dim3(256, 4, 8), blk, 0, stream>>>(x_u, xu_t, LU);

    // vk on u2d path (composed): V half transposed out, K half natural out
    gemm_bf16<0, 1><<<gAct, blk5, 0, stream>>>(Wvku, 0, 256, xu_t, act_bs, 256,
                                               bvku, 1.f, nullptr, nullptr, nullptr, zbuf, v_u2d_t, 256, 1);
    gemm_bf16<0, 0><<<gAct, blk5, 0, stream>>>(Wvku + 65536, 0, 256, xu_t, act_bs, 256,
                                               bvku + 256, 1.f, nullptr, nullptr, nullptr, zbuf, k_u2d, 256, 1);

    // scores_u2d (split-K) + softmax -> attn1
    gemm_bf16<0, 2><<<gS, blk5, 0, stream>>>(qds, cl_bs, LU, k_u2d, cl_bs, LU,
                                             nullptr, 0.f, nullptr, nullptr, nullptr, zbuf, Sp, LU, SPLIT);
    softmax_bf16<<<NB * NC, blk, 0, stream>>>(Sp, attn1, SPLIT);

    // down_output = x_d + (attn1 @ v_u2d)[l>>1]   (fused expand-add)
    gemm_bf16<0, 4><<<gAct, blk5, 0, stream>>>(attn1, (i64)NC * NC, 256, v_u2d_t, act_bs, 256,
                                               nullptr, 0.f, nullptr, nullptr, x_d, zbuf, out_dn, 256, 1);

    // vk on d2u path (PLAIN vk_w)
    gemm_bf16<0, 1><<<gAct, blk5, 0, stream>>>(Wvk, 0, 256, d2u_t, act_bs, 256,
                                               vk_b, 1.f, nullptr, nullptr, nullptr, zbuf, v_d2u_t, 256, 1);
    gemm_bf16<0, 0><<<gAct, blk5, 0, stream>>>(Wvk + 65536, 0, 256, d2u_t, act_bs, 256,
                                               vk_b + 256, 1.f, nullptr, nullptr, nullptr, zbuf, k_d2u, 256, 1);

    // q_u = q_w @ x_u + q_b  (natural [c][l]) -- overwrites d2u_t region (dead)
    gemm_bf16<0, 0><<<gAct, blk5, 0, stream>>>(Qw, 0, 256, xu_t, act_bs, 256,
                                               q_b, 1.f, nullptr, nullptr, nullptr, zbuf, q_u, 256, 1);

    // scores_d2u + softmax -> attn2
    gemm_bf16<0, 2><<<gS, blk5, 0, stream>>>(q_u, cl_bs, LU, k_d2u, cl_bs, LU,
                                             nullptr, 0.f, nullptr, nullptr, nullptr, zbuf, Sp, LU, SPLIT);
    softmax_bf16<<<NB * NC, blk, 0, stream>>>(Sp, attn2, SPLIT);

    // up_output = x_u + attn2 @ v_d2u
    gemm_bf16<0, 3><<<gAct, blk5, 0, stream>>>(attn2, (i64)NC * NC, 256, v_d2u_t, act_bs, 256,
                                               nullptr, 0.f, nullptr, nullptr, x_u, zbuf, out_up, 256, 1);
}